// Round 1
// baseline (297.833 us; speedup 1.0000x reference)
//
#include <hip/hip_runtime.h>

#define N_IN   16384
#define N_OUT  16384
#define KSZ    9
#define CIN    32
#define COUT   32
#define BC     64
#define NCB    512         // fine buckets = io >> 5  (32 n each)
#define CHA    4096        // bin chunk
#define ECAP_F 4096        // sivF slots per fine bucket (mean 2930, +20 sigma)
#define ROWS   288         // 9 k * 32 n per fine slice
#define PHROWS 96          // 3 k per einsum phase
#define XSTR   68          // sxk row stride: %32==4, 16B-aligned rows

union PrepSH {
    struct { int cnt[NCB]; int cntE[NCB]; int gbase[NCB]; int cursor[NCB];
             int segsum[8]; float2 slist[CHA]; } bin;   // 40.0 KB
    struct { float tile[64 * 65]; } xqp;                // 16.6 KB
};

// ---------------------------------------------------------------------------
// k_prep: blocks [0,nchA) bin entries into 512 FINE buckets (one per 32-n
// output slice) with LDS staging + run-coalesced flush; blocks
// [nchA, nchA+256) transpose x into xq; block nchA+256 transposes w.
// payload = fid<<23 | in<<9 | (k*32 + (o&31)).
__global__ __launch_bounds__(512) void k_prep(
        const float* __restrict__ x, const float* __restrict__ qw,
        const float* __restrict__ vals, const float* __restrict__ w,
        const int* __restrict__ ik, const int* __restrict__ io,
        const int* __restrict__ ii, float* __restrict__ xq,
        float2* __restrict__ sivF, int* __restrict__ gcntF,
        float* __restrict__ wT, int nnz, int nchA) {
    __shared__ PrepSH sh;
    const int t = threadIdx.x;
    const int bid = blockIdx.x;

    if (bid >= nchA) {
        if (bid < nchA + 256) {
            const int in0 = (bid - nchA) * 64;
#pragma unroll
            for (int i = 0; i < 8; ++i) {
                int idx = t + i * 512;
                int bcl = idx >> 6, inl = idx & 63;
                sh.xqp.tile[bcl * 65 + inl] = x[bcl * N_IN + in0 + inl];
            }
            __syncthreads();
#pragma unroll
            for (int i = 0; i < 8; ++i) {
                int idx = t + i * 512;
                int inl = idx >> 6, bcl = idx & 63;
                xq[(size_t)(in0 + inl) * BC + bcl] = sh.xqp.tile[bcl * 65 + inl] * qw[in0 + inl];
            }
        } else {
            for (int i = t; i < COUT * CIN * KSZ; i += 512) {
                int o = i / (CIN * KSZ);
                int r = i - o * (CIN * KSZ);
                int c = r / KSZ;
                int k = r - c * KSZ;
                wT[((k * 8 + (o >> 2)) * 32 + c) * 4 + (o & 3)] = w[i];
            }
        }
        return;
    }

    // ---- binning block
    sh.bin.cnt[t] = 0;
    __syncthreads();
    const int base = bid * CHA;
    const int e0   = base + t * 8;

    float vv[8]; int pk[8]; int bk[8]; bool hv[8];
    if (e0 + 8 <= nnz) {
        int4 a0 = *(const int4*)(io + e0),  a1 = *(const int4*)(io + e0 + 4);
        int4 b0 = *(const int4*)(ii + e0),  b1 = *(const int4*)(ii + e0 + 4);
        int4 k0 = *(const int4*)(ik + e0),  k1 = *(const int4*)(ik + e0 + 4);
        float4 d0 = *(const float4*)(vals + e0), d1 = *(const float4*)(vals + e0 + 4);
        int ov[8] = {a0.x, a0.y, a0.z, a0.w, a1.x, a1.y, a1.z, a1.w};
        int iv[8] = {b0.x, b0.y, b0.z, b0.w, b1.x, b1.y, b1.z, b1.w};
        int kv[8] = {k0.x, k0.y, k0.z, k0.w, k1.x, k1.y, k1.z, k1.w};
        float dv[8] = {d0.x, d0.y, d0.z, d0.w, d1.x, d1.y, d1.z, d1.w};
#pragma unroll
        for (int j = 0; j < 8; ++j) {
            hv[j] = true;
            bk[j] = ov[j] >> 5;
            pk[j] = (int)(((unsigned)(ov[j] >> 5)) << 23) | (iv[j] << 9) | (kv[j] * 32 + (ov[j] & 31));
            vv[j] = dv[j];
        }
    } else {
#pragma unroll
        for (int j = 0; j < 8; ++j) {
            int e = e0 + j;
            hv[j] = (e < nnz);
            if (hv[j]) {
                int o = io[e];
                bk[j] = o >> 5;
                pk[j] = (int)(((unsigned)(o >> 5)) << 23) | (ii[e] << 9) | (ik[e] * 32 + (o & 31));
                vv[j] = vals[e];
            } else { bk[j] = 0; pk[j] = 0; vv[j] = 0.f; }
        }
    }
#pragma unroll
    for (int j = 0; j < 8; ++j) if (hv[j]) atomicAdd(&sh.bin.cnt[bk[j]], 1);
    __syncthreads();

    // gbase via global alloc + parallel exclusive scan of all 512 counts
    const int lane = t & 63;
    const int wvp  = t >> 6;
    const int cv = sh.bin.cnt[t];
    sh.bin.gbase[t] = t * ECAP_F + (cv ? atomicAdd(&gcntF[t], cv) : 0);
    int v = cv;
#pragma unroll
    for (int off = 1; off < 64; off <<= 1) {
        int u = __shfl_up(v, off);
        if (lane >= off) v += u;
    }
    if (lane == 63) sh.bin.segsum[wvp] = v;
    __syncthreads();
    if (t == 0) {
        int c = 0;
#pragma unroll
        for (int s = 0; s < 8; ++s) { int xs = sh.bin.segsum[s]; sh.bin.segsum[s] = c; c += xs; }
    }
    __syncthreads();
    const int excl = v - cv + sh.bin.segsum[wvp];
    sh.bin.cntE[t]   = excl;
    sh.bin.cursor[t] = excl;
    __syncthreads();
#pragma unroll
    for (int j = 0; j < 8; ++j) {
        if (hv[j]) {
            int pos = atomicAdd(&sh.bin.cursor[bk[j]], 1);
            sh.bin.slist[pos] = make_float2(vv[j], __int_as_float(pk[j]));
        }
    }
    __syncthreads();
    const int m = min(nnz - base, CHA);
    for (int p = t; p < m; p += 512) {
        float2 f2 = sh.bin.slist[p];
        int cb = (int)((unsigned)__float_as_int(f2.y) >> 23);
        int dest = sh.bin.gbase[cb] + (p - sh.bin.cntE[cb]);
        if (dest < (cb + 1) * ECAP_F) sivF[dest] = f2;
    }
}

// ---------------------------------------------------------------------------
// k_fused7: one 1024-thread block per 32-n fine slice (512 blocks, 2/CU,
// 32 waves/CU). Reads ONLY its own entries (no filter pass): count rows from
// global (payload word only), scan 288, scatter global->LDS sorted; 3 k-phases
// of 96 rows with per-wave register accumulation (no sxk zeroing - every row
// written); full-wave einsum (2 batch x 32 n lanes, o-pair per wave so weight
// pointers stay wave-uniform -> s_load).
__global__ __launch_bounds__(1024, 8) void k_fused7(const float* __restrict__ xq,
        const float2* __restrict__ sivF, const int* __restrict__ gcntF,
        const float* __restrict__ wT, const float* __restrict__ bias,
        float* __restrict__ out) {
    __shared__ __align__(16) float sxk[PHROWS * XSTR];   // 26112 B
    __shared__ __align__(16) float2 slist[ECAP_F];       // 32768 B
    __shared__ int rowStart[ROWS + 1];
    __shared__ int cursor[ROWS];
    const int tid  = threadIdx.x;
    const int lane = tid & 63;
    const int wv   = __builtin_amdgcn_readfirstlane(tid >> 6);   // 0..15
    const unsigned f = blockIdx.x;

    if (tid < ROWS) rowStart[tid] = 0;
    __syncthreads();

    const int mF = min(gcntF[f], ECAP_F);
    const float2* __restrict__ src = sivF + (size_t)f * ECAP_F;
    const int* __restrict__ srcI = (const int*)src;
    for (int i = tid; i < mF; i += 1024)
        atomicAdd(&rowStart[srcI[2 * i + 1] & 0x1FF], 1);
    __syncthreads();

    if (wv == 0) {   // exclusive scan over 288 counts
        int carry = 0;
#pragma unroll
        for (int i0 = 0; i0 < 320; i0 += 64) {
            int idx = i0 + lane;
            int v = (idx < ROWS) ? rowStart[idx] : 0;
            int orig = v;
#pragma unroll
            for (int off = 1; off < 64; off <<= 1) {
                int u = __shfl_up(v, off);
                if (lane >= off) v += u;
            }
            if (idx < ROWS) {
                int excl = carry + v - orig;
                rowStart[idx] = excl;
                cursor[idx]   = excl;
            }
            carry += __shfl(v, 63);
        }
        if (lane == 0) rowStart[ROWS] = carry;
    }
    __syncthreads();

    // global->LDS scatter, sorted by row; strip payload to xq byte offset
    for (int i = tid; i < mF; i += 1024) {
        float2 v = src[i];
        int p = __float_as_int(v.y);
        int pos = atomicAdd(&cursor[p & 0x1FF], 1);
        slist[pos] = make_float2(v.x, __int_as_float((p >> 1) & 0x3FFF00));
    }
    __syncthreads();

    const char* xqb   = (const char*)xq;
    const int   lane4 = lane * 4;
    const int   b_    = lane >> 5;          // batch
    const int   n32   = lane & 31;          // n within slice
    const int   oq    = wv >> 1;            // o quad 0..7
    const int   ol    = (wv & 1) * 2;       // o offset within quad: 0 or 2
    float acc[2] = {0.f, 0.f};

#pragma unroll
    for (int ph = 0; ph < 3; ++ph) {
        const int rbase = ph * PHROWS;
        for (int r = rbase + wv; r < rbase + PHROWS; r += 16) {
            const int a = rowStart[r], b = rowStart[r + 1];
            float acc0 = 0.f, acc1 = 0.f, acc2 = 0.f, acc3 = 0.f;
            int i = a;
            for (; i + 7 < b; i += 8) {
                float2 v0 = slist[i],     v1 = slist[i + 1], v2 = slist[i + 2], v3 = slist[i + 3];
                float2 v4 = slist[i + 4], v5 = slist[i + 5], v6 = slist[i + 6], v7 = slist[i + 7];
                acc0 += *(const float*)(xqb + (__float_as_int(v0.y) + lane4)) * v0.x;
                acc1 += *(const float*)(xqb + (__float_as_int(v1.y) + lane4)) * v1.x;
                acc2 += *(const float*)(xqb + (__float_as_int(v2.y) + lane4)) * v2.x;
                acc3 += *(const float*)(xqb + (__float_as_int(v3.y) + lane4)) * v3.x;
                acc0 += *(const float*)(xqb + (__float_as_int(v4.y) + lane4)) * v4.x;
                acc1 += *(const float*)(xqb + (__float_as_int(v5.y) + lane4)) * v5.x;
                acc2 += *(const float*)(xqb + (__float_as_int(v6.y) + lane4)) * v6.x;
                acc3 += *(const float*)(xqb + (__float_as_int(v7.y) + lane4)) * v7.x;
            }
            for (; i + 3 < b; i += 4) {
                float2 v0 = slist[i], v1 = slist[i + 1], v2 = slist[i + 2], v3 = slist[i + 3];
                acc0 += *(const float*)(xqb + (__float_as_int(v0.y) + lane4)) * v0.x;
                acc1 += *(const float*)(xqb + (__float_as_int(v1.y) + lane4)) * v1.x;
                acc2 += *(const float*)(xqb + (__float_as_int(v2.y) + lane4)) * v2.x;
                acc3 += *(const float*)(xqb + (__float_as_int(v3.y) + lane4)) * v3.x;
            }
            for (; i < b; ++i) {
                float2 v = slist[i];
                acc0 += *(const float*)(xqb + (__float_as_int(v.y) + lane4)) * v.x;
            }
            // every row in [rbase, rbase+96) written by exactly one wave -> no zeroing
            sxk[(r - rbase) * XSTR + lane] = (acc0 + acc1) + (acc2 + acc3);
        }
        __syncthreads();
        const int kbase = ph * 3;
#pragma unroll
        for (int kk = 0; kk < 3; ++kk) {
            const float* xr = &sxk[(kk * 32 + n32) * XSTR + b_ * 32];
            const float* wp = &wT[((kbase + kk) * 8 + oq) * 128 + ol];   // uniform -> s_load
#pragma unroll
            for (int c4 = 0; c4 < 8; ++c4) {
                float4 xv = *(const float4*)&xr[c4 * 4];
#pragma unroll
                for (int cc = 0; cc < 4; ++cc) {
                    float xval = (&xv.x)[cc];
                    acc[0] += xval * wp[(c4 * 4 + cc) * 4];
                    acc[1] += xval * wp[(c4 * 4 + cc) * 4 + 1];
                }
            }
        }
        __syncthreads();
    }

    const int n0 = (int)f * 32;
#pragma unroll
    for (int j = 0; j < 2; ++j) {
        int o = oq * 4 + ol + j;
        out[((size_t)b_ * COUT + o) * N_OUT + n0 + n32] = acc[j] + bias[o];
    }
}

// ---------------------------------------------------------------------------
extern "C" void kernel_launch(void* const* d_in, const int* in_sizes, int n_in,
                              void* d_out, int out_size, void* d_ws, size_t ws_size,
                              hipStream_t stream) {
    const float* x    = (const float*)d_in[0];
    const float* qw   = (const float*)d_in[1];
    const float* vals = (const float*)d_in[2];
    const float* w    = (const float*)d_in[3];
    const float* bias = (const float*)d_in[4];
    const int*   ik   = (const int*)d_in[5];
    const int*   io   = (const int*)d_in[6];
    const int*   ii   = (const int*)d_in[7];
    const int    nnz  = in_sizes[2];
    const int    nchA = (nnz + CHA - 1) / CHA;

    char* ws = (char*)d_ws;
    float*  xq    = (float*)ws;  ws += (size_t)N_IN * BC * 4;        // 4 MB
    float2* sivF  = (float2*)ws; ws += (size_t)NCB * ECAP_F * 8;     // 16.78 MB
    int*    gcntF = (int*)ws;    ws += NCB * 4;
    float*  wT    = (float*)ws;  ws += (size_t)COUT * CIN * KSZ * 4;

    hipMemsetAsync(gcntF, 0, NCB * sizeof(int), stream);
    k_prep  <<<nchA + 257, 512, 0, stream>>>(x, qw, vals, w, ik, io, ii,
                                             xq, sivF, gcntF, wT, nnz, nchA);
    k_fused7<<<NCB, 1024, 0, stream>>>(xq, sivF, gcntF, wT, bias, (float*)d_out);
}

// Round 2
// 174.032 us; speedup vs baseline: 1.7114x; 1.7114x over previous
//
#include <hip/hip_runtime.h>

#define N_IN   16384
#define N_OUT  16384
#define KSZ    9
#define CIN    32
#define COUT   32
#define BC     64
#define NCB    1024        // fine buckets = io >> 4  (16 n each)
#define CHA    4096        // bin chunk
#define ECAP_F 2048        // sivF slots per fine bucket (mean 1465, +15 sigma)
#define GSTR   16          // gcnt stride in ints: one counter per 64B line
#define ROWS   144         // 9 k * 16 n per fine slice
#define XSTR   68          // sxk row stride: %32==4 -> max 4-way on b128, 16B-aligned

union PrepSH {
    struct { int cnt[NCB]; int cntE[NCB]; int gbase[NCB]; int cursor[NCB];
             int segsum[8]; float2 slist[CHA]; } bin;   // 48.1 KB
    struct { float tile[64 * 65]; } xqp;                // 16.6 KB
};

// ---------------------------------------------------------------------------
// k_prep: blocks [0,nchA) bin entries into 1024 FINE buckets (one per 16-n
// output slice) with LDS staging + run-coalesced flush; blocks
// [nchA, nchA+256) transpose x into xq; block nchA+256 transposes w.
// payload = (io>>4)<<22 | in<<8 | (k*16 + (io&15))   -- identical to fused6.
// gcnt is padded to one counter per 64B cache line (GSTR) so the per-chunk
// per-bucket global atomics parallelize across L2 lines.
__global__ __launch_bounds__(512) void k_prep(
        const float* __restrict__ x, const float* __restrict__ qw,
        const float* __restrict__ vals, const float* __restrict__ w,
        const int* __restrict__ ik, const int* __restrict__ io,
        const int* __restrict__ ii, float* __restrict__ xq,
        float2* __restrict__ sivF, int* __restrict__ gcntF,
        float* __restrict__ wT, int nnz, int nchA) {
    __shared__ PrepSH sh;
    const int t = threadIdx.x;
    const int bid = blockIdx.x;

    if (bid >= nchA) {
        if (bid < nchA + 256) {
            const int in0 = (bid - nchA) * 64;
#pragma unroll
            for (int i = 0; i < 8; ++i) {
                int idx = t + i * 512;
                int bcl = idx >> 6, inl = idx & 63;
                sh.xqp.tile[bcl * 65 + inl] = x[bcl * N_IN + in0 + inl];
            }
            __syncthreads();
#pragma unroll
            for (int i = 0; i < 8; ++i) {
                int idx = t + i * 512;
                int inl = idx >> 6, bcl = idx & 63;
                xq[(size_t)(in0 + inl) * BC + bcl] = sh.xqp.tile[bcl * 65 + inl] * qw[in0 + inl];
            }
        } else {
            for (int i = t; i < COUT * CIN * KSZ; i += 512) {
                int o = i / (CIN * KSZ);
                int r = i - o * (CIN * KSZ);
                int c = r / KSZ;
                int k = r - c * KSZ;
                wT[((k * 8 + (o >> 2)) * 32 + c) * 4 + (o & 3)] = w[i];
            }
        }
        return;
    }

    // ---- binning block
    sh.bin.cnt[t] = 0;
    sh.bin.cnt[t + 512] = 0;
    __syncthreads();
    const int base = bid * CHA;
    const int e0   = base + t * 8;

    float vv[8]; int pk[8]; int bk[8]; bool hv[8];
    if (e0 + 8 <= nnz) {
        int4 a0 = *(const int4*)(io + e0),  a1 = *(const int4*)(io + e0 + 4);
        int4 b0 = *(const int4*)(ii + e0),  b1 = *(const int4*)(ii + e0 + 4);
        int4 k0 = *(const int4*)(ik + e0),  k1 = *(const int4*)(ik + e0 + 4);
        float4 d0 = *(const float4*)(vals + e0), d1 = *(const float4*)(vals + e0 + 4);
        int ov[8] = {a0.x, a0.y, a0.z, a0.w, a1.x, a1.y, a1.z, a1.w};
        int iv[8] = {b0.x, b0.y, b0.z, b0.w, b1.x, b1.y, b1.z, b1.w};
        int kv[8] = {k0.x, k0.y, k0.z, k0.w, k1.x, k1.y, k1.z, k1.w};
        float dv[8] = {d0.x, d0.y, d0.z, d0.w, d1.x, d1.y, d1.z, d1.w};
#pragma unroll
        for (int j = 0; j < 8; ++j) {
            hv[j] = true;
            bk[j] = ov[j] >> 4;
            pk[j] = (int)(((unsigned)(ov[j] >> 4) << 22)) | (iv[j] << 8) | (kv[j] * 16 + (ov[j] & 15));
            vv[j] = dv[j];
        }
    } else {
#pragma unroll
        for (int j = 0; j < 8; ++j) {
            int e = e0 + j;
            hv[j] = (e < nnz);
            if (hv[j]) {
                int o = io[e];
                bk[j] = o >> 4;
                pk[j] = (int)(((unsigned)(o >> 4) << 22)) | (ii[e] << 8) | (ik[e] * 16 + (o & 15));
                vv[j] = vals[e];
            } else { bk[j] = 0; pk[j] = 0; vv[j] = 0.f; }
        }
    }
#pragma unroll
    for (int j = 0; j < 8; ++j) if (hv[j]) atomicAdd(&sh.bin.cnt[bk[j]], 1);
    __syncthreads();

    // gbase via padded global alloc + parallel exclusive scan of 1024 counts:
    // wave wvp scans buckets [wvp*128, (wvp+1)*128) in two 64-chunks.
    const int lane = t & 63;
    const int wvp  = t >> 6;
    int cvv[2], exclv[2];
    {
        int carry = 0;
#pragma unroll
        for (int s = 0; s < 2; ++s) {
            const int idx = wvp * 128 + s * 64 + lane;
            const int cv = sh.bin.cnt[idx];
            cvv[s] = cv;
            sh.bin.gbase[idx] = idx * ECAP_F + (cv ? atomicAdd(&gcntF[idx * GSTR], cv) : 0);
            int v = cv;
#pragma unroll
            for (int off = 1; off < 64; off <<= 1) {
                int u = __shfl_up(v, off);
                if (lane >= off) v += u;
            }
            exclv[s] = carry + v - cv;
            carry += __shfl(v, 63);
        }
        if (lane == 0) sh.bin.segsum[wvp] = carry;
    }
    __syncthreads();
    if (t == 0) {
        int c = 0;
#pragma unroll
        for (int s = 0; s < 8; ++s) { int xs = sh.bin.segsum[s]; sh.bin.segsum[s] = c; c += xs; }
    }
    __syncthreads();
#pragma unroll
    for (int s = 0; s < 2; ++s) {
        const int idx = wvp * 128 + s * 64 + lane;
        const int e = exclv[s] + sh.bin.segsum[wvp];
        sh.bin.cntE[idx]   = e;
        sh.bin.cursor[idx] = e;
    }
    __syncthreads();
#pragma unroll
    for (int j = 0; j < 8; ++j) {
        if (hv[j]) {
            int pos = atomicAdd(&sh.bin.cursor[bk[j]], 1);
            sh.bin.slist[pos] = make_float2(vv[j], __int_as_float(pk[j]));
        }
    }
    __syncthreads();
    const int m = min(nnz - base, CHA);
    for (int p = t; p < m; p += 512) {
        float2 f2 = sh.bin.slist[p];
        int cb = (int)((unsigned)__float_as_int(f2.y) >> 22);
        int dest = sh.bin.gbase[cb] + (p - sh.bin.cntE[cb]);
        if (dest < (cb + 1) * ECAP_F) sivF[dest] = f2;
    }
}

// ---------------------------------------------------------------------------
// k_fused8: proven fused6 structure (512 threads, 1024 blocks of 16-n slices)
// minus the coarse-bucket filter pass: each block reads ONLY its own bucket.
// Count rows from global payloads, scan 144, scatter global->LDS sorted
// (payload stripped to xq byte offset); per-wave register accumulation;
// half-wave einsum with wave-uniform weight pointers (s_load).
__global__ __launch_bounds__(512) void k_fused8(const float* __restrict__ xq,
        const float2* __restrict__ sivF, const int* __restrict__ gcntF,
        const float* __restrict__ wT, const float* __restrict__ bias,
        float* __restrict__ out) {
    __shared__ __align__(16) float sxk[80 * XSTR];   // 21760 B
    __shared__ __align__(16) float2 slist[ECAP_F];   // 16384 B
    __shared__ int    rowStart[ROWS + 1];
    __shared__ int    cursor[ROWS];
    const int tid  = threadIdx.x;
    const int lane = tid & 63;
    const int wv   = __builtin_amdgcn_readfirstlane(tid >> 6);
    const unsigned f = blockIdx.x;

    if (tid < ROWS) rowStart[tid] = 0;
    __syncthreads();

    const int mF = min(gcntF[f * GSTR], ECAP_F);
    const float2* __restrict__ src = sivF + (size_t)f * ECAP_F;
    const int* __restrict__ srcI = (const int*)src;
    for (int i = tid; i < mF; i += 512)
        atomicAdd(&rowStart[srcI[2 * i + 1] & 0xFF], 1);
    __syncthreads();

    if (wv == 0) {   // exclusive scan over 144 counts
        int carry = 0;
#pragma unroll
        for (int i0 = 0; i0 < 192; i0 += 64) {
            int idx = i0 + lane;
            int v = (idx < ROWS) ? rowStart[idx] : 0;
            int orig = v;
#pragma unroll
            for (int off = 1; off < 64; off <<= 1) {
                int u = __shfl_up(v, off);
                if (lane >= off) v += u;
            }
            if (idx < ROWS) {
                int excl = carry + v - orig;
                rowStart[idx] = excl;
                cursor[idx]   = excl;
            }
            carry += __shfl(v, 63);
        }
        if (lane == 0) rowStart[ROWS] = carry;
    }
    __syncthreads();
    // global->LDS scatter, sorted by row; strip payload to xq byte offset
    for (int i = tid; i < mF; i += 512) {
        float2 v = src[i];
        int p = __float_as_int(v.y);
        int pos = atomicAdd(&cursor[p & 0xFF], 1);
        slist[pos] = make_float2(v.x, __int_as_float(p & 0x3FFF00));
    }
    __syncthreads();

    const char* xqb   = (const char*)xq;
    const int   lane4 = lane * 4;
    const int   h     = lane >> 4;
    const int   nl    = lane & 15;
    float acc[4] = {0.f, 0.f, 0.f, 0.f};

#pragma unroll
    for (int ph = 0; ph < 2; ++ph) {
        const int rbase = ph ? 80 : 0;
        const int rend  = ph ? 144 : 80;
        const int nrows = rend - rbase;
        for (int i = tid; i < nrows * XSTR; i += 512) sxk[i] = 0.f;
        __syncthreads();
        for (int r = rbase + wv; r < rend; r += 8) {
            const int a = rowStart[r], b = rowStart[r + 1];
            if (a >= b) continue;
            float acc0 = 0.f, acc1 = 0.f, acc2 = 0.f, acc3 = 0.f;
            int i = a;
            for (; i + 7 < b; i += 8) {
                float2 v0 = slist[i],     v1 = slist[i + 1], v2 = slist[i + 2], v3 = slist[i + 3];
                float2 v4 = slist[i + 4], v5 = slist[i + 5], v6 = slist[i + 6], v7 = slist[i + 7];
                acc0 += *(const float*)(xqb + (__float_as_int(v0.y) + lane4)) * v0.x;
                acc1 += *(const float*)(xqb + (__float_as_int(v1.y) + lane4)) * v1.x;
                acc2 += *(const float*)(xqb + (__float_as_int(v2.y) + lane4)) * v2.x;
                acc3 += *(const float*)(xqb + (__float_as_int(v3.y) + lane4)) * v3.x;
                acc0 += *(const float*)(xqb + (__float_as_int(v4.y) + lane4)) * v4.x;
                acc1 += *(const float*)(xqb + (__float_as_int(v5.y) + lane4)) * v5.x;
                acc2 += *(const float*)(xqb + (__float_as_int(v6.y) + lane4)) * v6.x;
                acc3 += *(const float*)(xqb + (__float_as_int(v7.y) + lane4)) * v7.x;
            }
            for (; i + 3 < b; i += 4) {
                float2 v0 = slist[i], v1 = slist[i + 1], v2 = slist[i + 2], v3 = slist[i + 3];
                acc0 += *(const float*)(xqb + (__float_as_int(v0.y) + lane4)) * v0.x;
                acc1 += *(const float*)(xqb + (__float_as_int(v1.y) + lane4)) * v1.x;
                acc2 += *(const float*)(xqb + (__float_as_int(v2.y) + lane4)) * v2.x;
                acc3 += *(const float*)(xqb + (__float_as_int(v3.y) + lane4)) * v3.x;
            }
            for (; i < b; ++i) {
                float2 v = slist[i];
                acc0 += *(const float*)(xqb + (__float_as_int(v.y) + lane4)) * v.x;
            }
            sxk[(r - rbase) * XSTR + lane] = (acc0 + acc1) + (acc2 + acc3);
        }
        __syncthreads();
        if (lane < 32) {
            const int kbase = ph ? 5 : 0;
            const int kcnt  = ph ? 4 : 5;
            for (int kk = 0; kk < kcnt; ++kk) {
                const float* xr = &sxk[(kk * 16 + nl) * XSTR + h * 32];
                const float* wp = &wT[((kbase + kk) * 8 + wv) * 128];   // uniform -> s_load
#pragma unroll
                for (int c4 = 0; c4 < 8; ++c4) {
                    float4 xv = *(const float4*)&xr[c4 * 4];
#pragma unroll
                    for (int cc = 0; cc < 4; ++cc) {
                        float xval = (&xv.x)[cc];
#pragma unroll
                        for (int j = 0; j < 4; ++j)
                            acc[j] += xval * wp[(c4 * 4 + cc) * 4 + j];
                    }
                }
            }
        }
        __syncthreads();
    }

    if (lane < 32) {
        const int n0 = (int)f * 16;
#pragma unroll
        for (int j = 0; j < 4; ++j) {
            int o = wv * 4 + j;
            out[((size_t)h * COUT + o) * N_OUT + n0 + nl] = acc[j] + bias[o];
        }
    }
}

// ---------------------------------------------------------------------------
extern "C" void kernel_launch(void* const* d_in, const int* in_sizes, int n_in,
                              void* d_out, int out_size, void* d_ws, size_t ws_size,
                              hipStream_t stream) {
    const float* x    = (const float*)d_in[0];
    const float* qw   = (const float*)d_in[1];
    const float* vals = (const float*)d_in[2];
    const float* w    = (const float*)d_in[3];
    const float* bias = (const float*)d_in[4];
    const int*   ik   = (const int*)d_in[5];
    const int*   io   = (const int*)d_in[6];
    const int*   ii   = (const int*)d_in[7];
    const int    nnz  = in_sizes[2];
    const int    nchA = (nnz + CHA - 1) / CHA;

    char* ws = (char*)d_ws;
    float*  xq    = (float*)ws;  ws += (size_t)N_IN * BC * 4;            // 4 MB
    float2* sivF  = (float2*)ws; ws += (size_t)NCB * ECAP_F * 8;         // 16.78 MB
    int*    gcntF = (int*)ws;    ws += (size_t)NCB * GSTR * 4;           // 64 KB
    float*  wT    = (float*)ws;  ws += (size_t)COUT * CIN * KSZ * 4;

    hipMemsetAsync(gcntF, 0, (size_t)NCB * GSTR * sizeof(int), stream);
    k_prep  <<<nchA + 257, 512, 0, stream>>>(x, qw, vals, w, ik, io, ii,
                                             xq, sivF, gcntF, wT, nnz, nchA);
    k_fused8<<<NCB, 512, 0, stream>>>(xq, sivF, gcntF, wT, bias, (float*)d_out);
}